// Round 5
// baseline (530.149 us; speedup 1.0000x reference)
//
#include <hip/hip_runtime.h>

typedef unsigned short u16;
typedef __attribute__((ext_vector_type(4))) float  f32x4;
typedef __attribute__((ext_vector_type(4))) int    i32x4;
typedef __attribute__((ext_vector_type(4))) unsigned u32x4;
typedef __attribute__((ext_vector_type(8))) short  shortx8;

__device__ __constant__ float NF4C[16] = {
    -1.0f, -0.6962f, -0.5251f, -0.3949f, -0.2844f, -0.1848f, -0.0911f, 0.0f,
     0.0796f, 0.1609f, 0.2461f, 0.3379f, 0.4407f, 0.5626f, 0.723f, 1.0f};

__device__ __forceinline__ unsigned f2bf(float f) {
    unsigned u = __float_as_uint(f);
    return (u + 0x7FFFu + ((u >> 16) & 1u)) >> 16;   // RNE
}

__device__ __forceinline__ void ld_lds16(const u16* g, u16* l) {
    __builtin_amdgcn_global_load_lds(
        (const __attribute__((address_space(1))) void*)g,
        (__attribute__((address_space(3))) void*)l,
        16, 0, 0);
}

// ---------------- fused preprocessing (unchanged) ----------------

__global__ __launch_bounds__(256) void prep(const float* __restrict__ x,
                                            const int* __restrict__ qi,
                                            const float* __restrict__ sc,
                                            u16* __restrict__ xb,
                                            u16* __restrict__ wb) {
    const size_t nthr = (size_t)gridDim.x * 256;
    const size_t tid  = (size_t)blockIdx.x * 256 + threadIdx.x;

    for (size_t c = tid; c < (33554432u / 8); c += nthr) {
        const size_t i = c * 8;
        f32x4 f0 = __builtin_nontemporal_load((const f32x4*)(x + i));   // read-once
        f32x4 f1 = __builtin_nontemporal_load((const f32x4*)(x + i + 4));
        u32x4 o;
        o[0] = f2bf(f0[0]) | (f2bf(f0[1]) << 16);
        o[1] = f2bf(f0[2]) | (f2bf(f0[3]) << 16);
        o[2] = f2bf(f1[0]) | (f2bf(f1[1]) << 16);
        o[3] = f2bf(f1[2]) | (f2bf(f1[3]) << 16);
        *(u32x4*)(xb + i) = o;   // cached: GEMM re-reads from L2/L3
    }
    for (size_t c = tid; c < (16777216u / 8); c += nthr) {
        const size_t i = c * 8;
        const float s = sc[i >> 10];          // 8 consecutive elems share one block
        i32x4 q0 = __builtin_nontemporal_load((const i32x4*)(qi + i));  // read-once
        i32x4 q1 = __builtin_nontemporal_load((const i32x4*)(qi + i + 4));
        u32x4 o;
        o[0] = f2bf(NF4C[q0[0]] * s) | (f2bf(NF4C[q0[1]] * s) << 16);
        o[1] = f2bf(NF4C[q0[2]] * s) | (f2bf(NF4C[q0[3]] * s) << 16);
        o[2] = f2bf(NF4C[q1[0]] * s) | (f2bf(NF4C[q1[1]] * s) << 16);
        o[3] = f2bf(NF4C[q1[2]] * s) | (f2bf(NF4C[q1[3]] * s) << 16);
        *(u32x4*)(wb + i) = o;
    }
}

// ---------------- main GEMM: A via LDS, B direct-from-global (reg prefetch) -------
// A: [M,K] bf16 row-major (x), B: [N,K] bf16 row-major (W) -> C = A*B^T, fp32 [M,N]
//
// R5 post-mortem chain: R3 43% (8-barrier lockstep) -> R4 48% (min-sync, 2 bar).
// LDS arithmetic: frag reads 192KB + stage writes 64KB = 256KB/K-tile/CU ~ 1000cyc
// vs MFMA 620cyc/SIMD -> structural 62% ceiling (m201's number). Fix: remove B
// from LDS. B^T is K-major, so the MFMA B-fragment IS a contiguous 16B global
// read: lane quad*16+r16 of frag j reads B[(bn+wn+j*16+r16)*K + kt*64+ks*32+quad*8]
// (per row the 4 quads merge into one 64B transaction; wb = 32MiB, L3-resident,
// L2-hot: re-read by 4 m-blocks per XCD). LDS now: A frag reads 128KB + A stage
// 32KB = 160KB ~ 625cyc vs MFMA 620 -> ceiling ~97%.
//
// Per-wave B reg prefetch, half-tile dbuf (b0 = kstep0 frags, b1 = kstep1):
//   tile u body: issue A-stage(u+1)[4 gload_lds] ; b1 <- B(u,k1)[4 loads] ;
//   sched_barrier(0x78F: VMEM pinned, ALU/MFMA/DS free) ; P1/P2 MFMA with b0 ;
//   pb+=64, b0 <- B(u+1,k0) ; P3/P4 MFMA with b1 ; vmcnt(4) ; s_barrier.
// vmcnt ledger (in-order VMEM completion): per-tile issue order is
//   [A-stage x4][b1 x4][b0' x4]  (pinned by the sched_barrier + end asm fence).
//   Compiler's own wait for b1 before P3-MFMA is vmcnt(<=4) -> drains A-stage
//   (older). End-of-tile asm vmcnt(4): youngest 4 = b0' -> A-stage provably done
//   before s_barrier publishes buf^1. b0/b1 consumed via compiler reg-dep waits.
// WAR: stage into buf^1 is issued after the tile-(u-1) barrier, which all buf^1
//   readers (tile u-1) crossed only after their MFMAs consumed the reads. 1 bar/tile.
// Tail: u=62 (MODE 0) stages A(63) + preloads b0(63); u=63 (MODE 1) computes only.
//
// A-side XOR swizzle unchanged (0-conflict, verified R0-R4): LDS slot (row,c)
// holds global chunk c^(row&7); stage lane L sources chunk (L&7)^(L>>3) of row
// w*8+(L>>3); read key c0 = quad^(r16&7), c1 = c0^4 -> global chunks quad / quad+4.

#define BM 256
#define BN 256
#define BK 64

__device__ __forceinline__ f32x4 mfma16(shortx8 a, shortx8 b, f32x4 c) {
    return __builtin_amdgcn_mfma_f32_16x16x32_bf16(a, b, c, 0, 0, 0);
}

template<int MODE>   // 0 = steady (stage A(u+1), prefetch b0(u+1)), 1 = last tile
__device__ __forceinline__ void ktile(
    const u16* __restrict__ Ar,   // LDS read buf (block base)
    u16* dA,                      // LDS stage dest (wave base, buf^1)
    const u16* gA,                // per-lane global src, A tile u+1
    const u16** pb,               // per-lane B row ptrs (at tile u, kstep0)
    shortx8 (&b0)[4], shortx8 (&b1)[4],
    int wm, int r16, int c0, int c1,
    f32x4 (&acc)[8][4])
{
    constexpr size_t K = 4096;
    shortx8 a[4];

    if constexpr (MODE == 0) {
        ld_lds16(gA,                  dA);
        ld_lds16(gA + (size_t)64*K,   dA + 64*64);
        ld_lds16(gA + (size_t)128*K,  dA + 128*64);
        ld_lds16(gA + (size_t)192*K,  dA + 192*64);
    }
#pragma unroll
    for (int j = 0; j < 4; j++)
        b1[j] = *(const shortx8*)(pb[j] + 32);     // B(u, kstep1), +64B
    __builtin_amdgcn_sched_barrier(0x78F);         // pin VMEM order; ALU/MFMA/DS free

    // ---- P1: kstep0, rows [wm, wm+64) ----
#pragma unroll
    for (int i = 0; i < 4; i++)
        a[i] = *(const shortx8*)&Ar[(wm + i*16 + r16) * 64 + c0 * 8];
    __builtin_amdgcn_s_setprio(1);
#pragma unroll
    for (int i = 0; i < 4; i++)
#pragma unroll
        for (int j = 0; j < 4; j++)
            acc[i][j] = mfma16(a[i], b0[j], acc[i][j]);
    __builtin_amdgcn_s_setprio(0);

    // ---- P2: kstep0, rows [wm+64, wm+128) ----
#pragma unroll
    for (int i = 0; i < 4; i++)
        a[i] = *(const shortx8*)&Ar[(wm + 64 + i*16 + r16) * 64 + c0 * 8];
    __builtin_amdgcn_s_setprio(1);
#pragma unroll
    for (int i = 0; i < 4; i++)
#pragma unroll
        for (int j = 0; j < 4; j++)
            acc[4 + i][j] = mfma16(a[i], b0[j], acc[4 + i][j]);
    __builtin_amdgcn_s_setprio(0);

    if constexpr (MODE == 0) {
#pragma unroll
        for (int j = 0; j < 4; j++) {              // advance + prefetch B(u+1, kstep0)
            pb[j] += 64;
            b0[j] = *(const shortx8*)pb[j];
        }
    }

    // ---- P3: kstep1, rows [wm, wm+64) ----
#pragma unroll
    for (int i = 0; i < 4; i++)
        a[i] = *(const shortx8*)&Ar[(wm + i*16 + r16) * 64 + c1 * 8];
    __builtin_amdgcn_s_setprio(1);
#pragma unroll
    for (int i = 0; i < 4; i++)
#pragma unroll
        for (int j = 0; j < 4; j++)
            acc[i][j] = mfma16(a[i], b1[j], acc[i][j]);
    __builtin_amdgcn_s_setprio(0);

    // ---- P4: kstep1, rows [wm+64, wm+128) ----
#pragma unroll
    for (int i = 0; i < 4; i++)
        a[i] = *(const shortx8*)&Ar[(wm + 64 + i*16 + r16) * 64 + c1 * 8];
    __builtin_amdgcn_s_setprio(1);
#pragma unroll
    for (int i = 0; i < 4; i++)
#pragma unroll
        for (int j = 0; j < 4; j++)
            acc[4 + i][j] = mfma16(a[i], b1[j], acc[4 + i][j]);
    __builtin_amdgcn_s_setprio(0);

    if constexpr (MODE == 0) {
        asm volatile("s_waitcnt vmcnt(4)" ::: "memory");   // A(u+1) done (b0' youngest)
        asm volatile("s_barrier" ::: "memory");            // publish buf^1; WAR gate
    }
}

__global__ __launch_bounds__(512, 2) void gemm_bt(const u16* __restrict__ A,
                                                  const u16* __restrict__ B,
                                                  float* __restrict__ C) {
    constexpr size_t K = 4096;
    constexpr int N = 4096;
    __shared__ __align__(16) u16 As[2][BM * BK];   // 2 x 32 KiB = 64 KiB (A only)

    const int t    = threadIdx.x;
    const int wave = t >> 6;
    const int lane = t & 63;
    const int quad = lane >> 4;
    const int r16  = lane & 15;

    // XCD swizzle (512 blocks, 512%8==0 bijective): 4 m-tiles x 16 n-tiles per XCD
    const int id  = blockIdx.x;
    const int xcd = id & 7;
    const int loc = id >> 3;                       // 0..63
    const int bm  = (xcd * 4 + (loc >> 4)) * BM;   // 0..31 * 256
    const int bn  = (loc & 15) * BN;               // 0..15 * 256

    // A staging source (pre-swizzled): row w*8+(lane>>3), chunk (lane&7)^(lane>>3)
    const int lrow = (wave << 3) + (lane >> 3);
    const int lch  = (lane & 7) ^ (lane >> 3);
    const u16* sA = A + (size_t)(bm + lrow) * K + lch * 8;

    const int w512 = wave * 512;                   // wave slab within a 64-row quarter
    u16* dA0 = &As[0][w512];
    u16* dA1 = &As[1][w512];

    const int wm = (wave >> 2) * 128;              // wave tile 128(m) x 64(n)
    const int wn = (wave & 3) * 64;
    const int c0 = quad ^ (r16 & 7);               // kstep0 chunk key (A LDS read)
    const int c1 = c0 ^ 4;                         // kstep1

    // per-lane B row pointers (frag j), at tile 0 kstep0
    const u16* pb[4];
#pragma unroll
    for (int j = 0; j < 4; j++)
        pb[j] = B + (size_t)(bn + wn + j * 16 + r16) * K + quad * 8;

    f32x4 acc[8][4];
#pragma unroll
    for (int i = 0; i < 8; i++)
#pragma unroll
        for (int j = 0; j < 4; j++) acc[i][j] = (f32x4)0.0f;

    shortx8 b0[4], b1[4];

    // prologue: stage A(0) -> buf0; preload b0 = B(0,kstep0)
    ld_lds16(sA,                  dA0);
    ld_lds16(sA + (size_t)64*K,   dA0 + 64*64);
    ld_lds16(sA + (size_t)128*K,  dA0 + 128*64);
    ld_lds16(sA + (size_t)192*K,  dA0 + 192*64);
#pragma unroll
    for (int j = 0; j < 4; j++) b0[j] = *(const shortx8*)pb[j];
    asm volatile("s_waitcnt vmcnt(4)" ::: "memory");   // A(0) landed (b0 younger)
    asm volatile("s_barrier" ::: "memory");

    const u16* gA = sA + 64;   // staging src for tile u+1
#pragma unroll 1
    for (int u = 0; u < 62; u += 2) {
        ktile<0>(As[0], dA1, gA, pb, b0, b1, wm, r16, c0, c1, acc); gA += 64;
        ktile<0>(As[1], dA0, gA, pb, b0, b1, wm, r16, c0, c1, acc); gA += 64;
    }
    // u=62: reads buf0, stages A(63)->buf1, preloads b0(63). u=63: compute only.
    ktile<0>(As[0], dA1, gA, pb, b0, b1, wm, r16, c0, c1, acc);
    ktile<1>(As[1], nullptr, nullptr, pb, b0, b1, wm, r16, c0, c1, acc);

    // epilogue: C/D layout col=lane&15, row=quad*4+reg  [verified m89; refcheck'd]
#pragma unroll
    for (int i = 0; i < 8; i++) {
        const int row0 = bm + wm + i * 16 + quad * 4;
#pragma unroll
        for (int j = 0; j < 4; j++) {
            const int col = bn + wn + j * 16 + r16;
            float* cp = &C[(size_t)row0 * N + col];
#pragma unroll
            for (int v = 0; v < 4; ++v)
                cp[(size_t)v * N] = acc[i][j][v];
        }
    }
}

// ---------------- fallback (ws too small): fp32 tiled, dequant on the fly ----------------

__global__ __launch_bounds__(256) void fallback_gemm(const float* __restrict__ x,
                                                     const int* __restrict__ qi,
                                                     const float* __restrict__ sc,
                                                     float* __restrict__ y) {
    __shared__ float xs[16][16];
    __shared__ float wsm[16][17];
    const int tx = threadIdx.x, ty = threadIdx.y;
    const int m = blockIdx.y * 16 + ty;
    const int nrow = blockIdx.x * 16 + ty;   // W row loaded by this thread
    float acc = 0.f;
    for (int k0 = 0; k0 < 4096; k0 += 16) {
        xs[ty][tx] = x[(size_t)m * 4096 + k0 + tx];
        const size_t fi = (size_t)nrow * 4096 + k0 + tx;
        wsm[ty][tx] = NF4C[qi[fi]] * sc[fi >> 10];
        __syncthreads();
#pragma unroll
        for (int kk = 0; kk < 16; kk++) acc += xs[ty][kk] * wsm[tx][kk];
        __syncthreads();
    }
    y[(size_t)m * 4096 + blockIdx.x * 16 + tx] = acc;
}

// ---------------- launch ----------------

extern "C" void kernel_launch(void* const* d_in, const int* in_sizes, int n_in,
                              void* d_out, int out_size, void* d_ws, size_t ws_size,
                              hipStream_t stream) {
    const float* x  = (const float*)d_in[0];
    const int*   qi = (const int*)d_in[1];
    const float* sc = (const float*)d_in[2];
    float* y = (float*)d_out;

    const int M = 8192, N = 4096, K = 4096;
    const size_t xb_bytes = (size_t)M * K * 2;   // 64 MiB
    const size_t wb_bytes = (size_t)N * K * 2;   // 32 MiB

    if (ws_size >= xb_bytes + wb_bytes) {
        u16* xb = (u16*)d_ws;
        u16* wb = (u16*)((char*)d_ws + xb_bytes);
        prep<<<2048, 256, 0, stream>>>(x, qi, sc, xb, wb);
        gemm_bt<<<(M / BM) * (N / BN), 512, 0, stream>>>(xb, wb, y);
    } else {
        dim3 block(16, 16);
        dim3 grid(N / 16, M / 16);
        fallback_gemm<<<grid, block, 0, stream>>>(x, qi, sc, y);
    }
}

// Round 7
// 472.778 us; speedup vs baseline: 1.1213x; 1.1213x over previous
//
#include <hip/hip_runtime.h>

typedef unsigned short u16;
typedef __attribute__((ext_vector_type(4))) float  f32x4;
typedef __attribute__((ext_vector_type(4))) int    i32x4;
typedef __attribute__((ext_vector_type(4))) unsigned u32x4;
typedef __attribute__((ext_vector_type(8))) short  shortx8;

__device__ __constant__ float NF4C[16] = {
    -1.0f, -0.6962f, -0.5251f, -0.3949f, -0.2844f, -0.1848f, -0.0911f, 0.0f,
     0.0796f, 0.1609f, 0.2461f, 0.3379f, 0.4407f, 0.5626f, 0.723f, 1.0f};

__device__ __forceinline__ unsigned f2bf(float f) {
    unsigned u = __float_as_uint(f);
    return (u + 0x7FFFu + ((u >> 16) & 1u)) >> 16;   // RNE
}

__device__ __forceinline__ void ld_lds16(const u16* g, u16* l) {
    __builtin_amdgcn_global_load_lds(
        (const __attribute__((address_space(1))) void*)g,
        (__attribute__((address_space(3))) void*)l,
        16, 0, 0);
}

// ---------------- fused preprocessing (unchanged from R4) ----------------

__global__ __launch_bounds__(256) void prep(const float* __restrict__ x,
                                            const int* __restrict__ qi,
                                            const float* __restrict__ sc,
                                            u16* __restrict__ xb,
                                            u16* __restrict__ wb) {
    const size_t nthr = (size_t)gridDim.x * 256;
    const size_t tid  = (size_t)blockIdx.x * 256 + threadIdx.x;

    for (size_t c = tid; c < (33554432u / 8); c += nthr) {
        const size_t i = c * 8;
        f32x4 f0 = __builtin_nontemporal_load((const f32x4*)(x + i));   // read-once
        f32x4 f1 = __builtin_nontemporal_load((const f32x4*)(x + i + 4));
        u32x4 o;
        o[0] = f2bf(f0[0]) | (f2bf(f0[1]) << 16);
        o[1] = f2bf(f0[2]) | (f2bf(f0[3]) << 16);
        o[2] = f2bf(f1[0]) | (f2bf(f1[1]) << 16);
        o[3] = f2bf(f1[2]) | (f2bf(f1[3]) << 16);
        *(u32x4*)(xb + i) = o;   // cached: GEMM re-reads from L2/L3
    }
    for (size_t c = tid; c < (16777216u / 8); c += nthr) {
        const size_t i = c * 8;
        const float s = sc[i >> 10];          // 8 consecutive elems share one block
        i32x4 q0 = __builtin_nontemporal_load((const i32x4*)(qi + i));  // read-once
        i32x4 q1 = __builtin_nontemporal_load((const i32x4*)(qi + i + 4));
        u32x4 o;
        o[0] = f2bf(NF4C[q0[0]] * s) | (f2bf(NF4C[q0[1]] * s) << 16);
        o[1] = f2bf(NF4C[q0[2]] * s) | (f2bf(NF4C[q0[3]] * s) << 16);
        o[2] = f2bf(NF4C[q1[0]] * s) | (f2bf(NF4C[q1[1]] * s) << 16);
        o[3] = f2bf(NF4C[q1[2]] * s) | (f2bf(NF4C[q1[3]] * s) << 16);
        *(u32x4*)(wb + i) = o;
    }
}

// ---------------- main GEMM: 256x256, BK=64, min-sync (R4) + consolidation --------
// A: [M,K] bf16 row-major (x), B: [N,K] bf16 row-major (W) -> C = A*B^T, fp32 [M,N]
//
// R6 FAILED (absmax 178.5): epilogue was changed to the swapped-operand layout but
// the mfma call sites were NOT swapped -> per-16x16-block transposed output. R7
// fixes it: acc[i][j] = mfma(b[j], a[i], acc). Derivation vs m89-verified mapping
// (for mfma(X,Y): lane(quad,r16) reg v = dot(X_row(quad*4+v), Y_row(r16))):
//   mfma(b[j], a[i]) -> element C[m = wm+i*16+r16][n = wn+j*16+quad*4+v]
// -> epilogue stores one f32x4 (4 consecutive C columns) per frag. Same dot
// products per output element -> absmax identical to R4 (0.5).
//
// Sync ledger (unchanged, verified R4 at 253us/48%): per group u (read buf r=u&1):
//   P4pre BAR — WAR gate for Bq01(u+2) staged into CURRENT buf's B rows 0..127;
//     arrival implies all waves' P3 B-reads consumed (compiler lgkm waits precede
//     P3 MFMAs). P4's A ds_reads are hoisted above this barrier: they hit the As
//     array; the post-barrier stage writes Bs (disjoint) -> safe in flight across.
//   vmcnt(2)+P4post BAR — drains W[u]={Bq23,Aq02,Aq13}(u+1) (6 loads, issued
//     P1-P3), leaves C[u]={Bq01(u+2)} (2 loads) in flight; publishes tile u+1.
//   Prologue: tile0 (8 loads) + Bq01(1) (2 loads), vmcnt(2) = steady entry.
//   Tail: group 62 stages tile 63 at P1-P3, vmcnt(0); group 63 bare.
//
// XOR bank swizzle (0-conflict, verified R0-R5): LDS slot (row,c) holds global
// 16B chunk c^(row&7); stage lane L sources chunk (L&7)^(L>>3) of row w*8+(L>>3);
// read key c0 = quad^(r16&7) (kstep0), c1 = c0^4 (kstep1).

#define BM 256
#define BN 256
#define BK 64

__device__ __forceinline__ f32x4 mfma16(shortx8 a, shortx8 b, f32x4 c) {
    return __builtin_amdgcn_mfma_f32_16x16x32_bf16(a, b, c, 0, 0, 0);
}

template<int MODE>   // 0 = steady, 1 = penultimate (no P4 stage, vmcnt0), 2 = last
__device__ __forceinline__ void kgroup(
    const u16* __restrict__ Ar, const u16* __restrict__ Br,   // read bufs
    u16* dA1, u16* dB1,          // stage dest wave-bases, buf^1 (tile u+1)
    u16* dBc,                    // stage dest wave-base, current buf (tile u+2 B)
    const u16* gA1, const u16* gB1,   // per-lane staging src, tile u+1
    int wm, int wn, int r16, int c0, int c1,
    f32x4 (&acc)[8][4])
{
    constexpr size_t K = 4096;
    shortx8 a[4], a2[4], b[4];

    // ---- P1: acc[0..3], kstep0 ----
#pragma unroll
    for (int j = 0; j < 4; j++)
        b[j] = *(const shortx8*)&Br[(wn + j * 16 + r16) * 64 + c0 * 8];
#pragma unroll
    for (int i = 0; i < 4; i++)
        a[i] = *(const shortx8*)&Ar[(wm + i * 16 + r16) * 64 + c0 * 8];
    if constexpr (MODE <= 1) {
        ld_lds16(gB1 + 128 * K, dB1 + 128 * 64);   // Bq2 of u+1
        ld_lds16(gB1 + 192 * K, dB1 + 192 * 64);   // Bq3
    }
    __builtin_amdgcn_s_setprio(1);
#pragma unroll
    for (int i = 0; i < 4; i++)
#pragma unroll
        for (int j = 0; j < 4; j++)
            acc[i][j] = mfma16(b[j], a[i], acc[i][j]);   // SWAPPED operands (R7 fix)
    __builtin_amdgcn_s_setprio(0);

    // ---- P2: acc[4..7], kstep0 (b reused) ----
#pragma unroll
    for (int i = 0; i < 4; i++)
        a2[i] = *(const shortx8*)&Ar[(wm + 64 + i * 16 + r16) * 64 + c0 * 8];
    if constexpr (MODE <= 1) {
        ld_lds16(gA1,           dA1);              // Aq0 of u+1
        ld_lds16(gA1 + 128 * K, dA1 + 128 * 64);   // Aq2
    }
    __builtin_amdgcn_s_setprio(1);
#pragma unroll
    for (int i = 0; i < 4; i++)
#pragma unroll
        for (int j = 0; j < 4; j++)
            acc[4 + i][j] = mfma16(b[j], a2[i], acc[4 + i][j]);
    __builtin_amdgcn_s_setprio(0);

    // ---- P3: acc[0..3], kstep1 ----
#pragma unroll
    for (int j = 0; j < 4; j++)
        b[j] = *(const shortx8*)&Br[(wn + j * 16 + r16) * 64 + c1 * 8];
#pragma unroll
    for (int i = 0; i < 4; i++)
        a[i] = *(const shortx8*)&Ar[(wm + i * 16 + r16) * 64 + c1 * 8];
    if constexpr (MODE <= 1) {
        ld_lds16(gA1 +  64 * K, dA1 +  64 * 64);   // Aq1 of u+1
        ld_lds16(gA1 + 192 * K, dA1 + 192 * 64);   // Aq3
    }
    __builtin_amdgcn_s_setprio(1);
#pragma unroll
    for (int i = 0; i < 4; i++)
#pragma unroll
        for (int j = 0; j < 4; j++)
            acc[i][j] = mfma16(b[j], a[i], acc[i][j]);
    __builtin_amdgcn_s_setprio(0);

    // P4 A-reads hoisted above the barrier (As array; post-barrier stage hits Bs)
#pragma unroll
    for (int i = 0; i < 4; i++)
        a2[i] = *(const shortx8*)&Ar[(wm + 64 + i * 16 + r16) * 64 + c1 * 8];
    if constexpr (MODE == 0)
        asm volatile("s_barrier" ::: "memory");            // P4pre (B WAR)

    // ---- P4: acc[4..7], kstep1 ----
    if constexpr (MODE == 0) {
        ld_lds16(gB1 + 64,          dBc);              // Bq0 of u+2 -> current buf
        ld_lds16(gB1 + 64 + 64 * K, dBc + 64 * 64);    // Bq1
    }
    __builtin_amdgcn_s_setprio(1);
#pragma unroll
    for (int i = 0; i < 4; i++)
#pragma unroll
        for (int j = 0; j < 4; j++)
            acc[4 + i][j] = mfma16(b[j], a2[i], acc[4 + i][j]);
    __builtin_amdgcn_s_setprio(0);
    if constexpr (MODE == 0) {
        asm volatile("s_waitcnt vmcnt(2)" ::: "memory");   // drain W[u]: tile u+1 done
        asm volatile("s_barrier" ::: "memory");            // P4post: publish, buf switch
    } else if constexpr (MODE == 1) {
        asm volatile("s_waitcnt vmcnt(0)" ::: "memory");   // tail: tile 63 lands
        asm volatile("s_barrier" ::: "memory");
    }                                                      // MODE 2: no sync at all
}

__global__ __launch_bounds__(512, 2) void gemm_bt(const u16* __restrict__ A,
                                                  const u16* __restrict__ B,
                                                  float* __restrict__ C) {
    constexpr size_t K = 4096;
    constexpr int N = 4096;
    __shared__ __align__(16) u16 As[2][BM * BK];   // 2 x 32 KiB
    __shared__ __align__(16) u16 Bs[2][BN * BK];   // 2 x 32 KiB -> 128 KiB

    const int t    = threadIdx.x;
    const int wave = t >> 6;
    const int lane = t & 63;
    const int quad = lane >> 4;
    const int r16  = lane & 15;

    // XCD swizzle (512 blocks, 512%8==0 bijective): 4 m-tiles x 16 n-tiles per XCD
    const int id  = blockIdx.x;
    const int xcd = id & 7;
    const int loc = id >> 3;                       // 0..63
    const int bm  = (xcd * 4 + (loc >> 4)) * BM;   // 0..31 * 256
    const int bn  = (loc & 15) * BN;               // 0..15 * 256

    // per-lane staging source (pre-swizzled chunk): row w*8+(lane>>3), chunk (lane&7)^(lane>>3)
    const int lrow = (wave << 3) + (lane >> 3);
    const int lch  = (lane & 7) ^ (lane >> 3);
    const u16* sA = A + (size_t)(bm + lrow) * K + lch * 8;
    const u16* sB = B + (size_t)(bn + lrow) * K + lch * 8;

    const int w512 = wave * 512;                   // wave slab offset within a quarter
    u16* dA0 = &As[0][w512];  u16* dA1 = &As[1][w512];
    u16* dB0 = &Bs[0][w512];  u16* dB1 = &Bs[1][w512];

    const int wm = (wave >> 2) * 128;              // wave tile 128(m) x 64(n)
    const int wn = (wave & 3) * 64;
    const int c0 = quad ^ (r16 & 7);               // kstep0 chunk key
    const int c1 = c0 ^ 4;                         // kstep1

    f32x4 acc[8][4];
#pragma unroll
    for (int i = 0; i < 8; i++)
#pragma unroll
        for (int j = 0; j < 4; j++) acc[i][j] = (f32x4)0.0f;

    // prologue: tile 0 (8 quarters) -> buf0; tile 1 Bq0,Bq1 -> buf1.
#pragma unroll
    for (int r0 = 0; r0 < 256; r0 += 64) {
        ld_lds16(sA + (size_t)r0 * K, dA0 + r0 * 64);
        ld_lds16(sB + (size_t)r0 * K, dB0 + r0 * 64);
    }
    ld_lds16(sB + 64,                  dB1);
    ld_lds16(sB + 64 + (size_t)64 * K, dB1 + 64 * 64);
    asm volatile("s_waitcnt vmcnt(2)" ::: "memory");   // tile 0 landed; Bq01(1) in flight
    asm volatile("s_barrier" ::: "memory");

    const u16* gA1 = sA + 64;   // staging src base, tile u+1
    const u16* gB1 = sB + 64;
#pragma unroll 1
    for (int u = 0; u < 62; u += 2) {
        kgroup<0>(As[0], Bs[0], dA1, dB1, dB0, gA1, gB1, wm, wn, r16, c0, c1, acc);
        gA1 += 64; gB1 += 64;
        kgroup<0>(As[1], Bs[1], dA0, dB0, dB1, gA1, gB1, wm, wn, r16, c0, c1, acc);
        gA1 += 64; gB1 += 64;
    }
    // group 62 (buf0; stages tile 63 into buf1 at P1-P3; vmcnt(0)), group 63 (buf1)
    kgroup<1>(As[0], Bs[0], dA1, dB1, dB0, gA1, gB1, wm, wn, r16, c0, c1, acc);
    kgroup<2>(As[1], Bs[1], dA0, dB0, dB1, gA1, gB1, wm, wn, r16, c0, c1, acc);

    // epilogue (swapped-operand C/D layout): lane(quad,r16) reg v of acc[i][j]
    // holds C[bm+wm+i*16+r16][bn+wn+j*16+quad*4+v] -> one f32x4 store per frag.
#pragma unroll
    for (int i = 0; i < 8; i++) {
        const int row = bm + wm + i * 16 + r16;
#pragma unroll
        for (int j = 0; j < 4; j++) {
            const int col = bn + wn + j * 16 + quad * 4;
            *(f32x4*)&C[(size_t)row * N + col] = acc[i][j];
        }
    }
}

// ---------------- fallback (ws too small): fp32 tiled, dequant on the fly ----------------

__global__ __launch_bounds__(256) void fallback_gemm(const float* __restrict__ x,
                                                     const int* __restrict__ qi,
                                                     const float* __restrict__ sc,
                                                     float* __restrict__ y) {
    __shared__ float xs[16][16];
    __shared__ float wsm[16][17];
    const int tx = threadIdx.x, ty = threadIdx.y;
    const int m = blockIdx.y * 16 + ty;
    const int nrow = blockIdx.x * 16 + ty;   // W row loaded by this thread
    float acc = 0.f;
    for (int k0 = 0; k0 < 4096; k0 += 16) {
        xs[ty][tx] = x[(size_t)m * 4096 + k0 + tx];
        const size_t fi = (size_t)nrow * 4096 + k0 + tx;
        wsm[ty][tx] = NF4C[qi[fi]] * sc[fi >> 10];
        __syncthreads();
#pragma unroll
        for (int kk = 0; kk < 16; kk++) acc += xs[ty][kk] * wsm[tx][kk];
        __syncthreads();
    }
    y[(size_t)m * 4096 + blockIdx.x * 16 + tx] = acc;
}

// ---------------- launch ----------------

extern "C" void kernel_launch(void* const* d_in, const int* in_sizes, int n_in,
                              void* d_out, int out_size, void* d_ws, size_t ws_size,
                              hipStream_t stream) {
    const float* x  = (const float*)d_in[0];
    const int*   qi = (const int*)d_in[1];
    const float* sc = (const float*)d_in[2];
    float* y = (float*)d_out;

    const int M = 8192, N = 4096, K = 4096;
    const size_t xb_bytes = (size_t)M * K * 2;   // 64 MiB
    const size_t wb_bytes = (size_t)N * K * 2;   // 32 MiB

    if (ws_size >= xb_bytes + wb_bytes) {
        u16* xb = (u16*)d_ws;
        u16* wb = (u16*)((char*)d_ws + xb_bytes);
        prep<<<2048, 256, 0, stream>>>(x, qi, sc, xb, wb);
        gemm_bt<<<(M / BM) * (N / BN), 512, 0, stream>>>(xb, wb, y);
    } else {
        dim3 block(16, 16);
        dim3 grid(N / 16, M / 16);
        fallback_gemm<<<grid, block, 0, stream>>>(x, qi, sc, y);
    }
}